// Round 9
// baseline (85.457 us; speedup 1.0000x reference)
//
#include <hip/hip_runtime.h>

// Problem constants
#define BB   8
#define CIN  128
#define COUT 128
#define KS   7
#define HH   32
#define WWID 32
#define HW   1024
#define NG   8     // dynamic-weight groups
#define GC   16    // channels per group
#define MROWS 768  // 256 t-rows + 512 v-rows
#define TROWS 256
#define VROWS 512
#define KDIM 512
#define WMAP_O 392  // 49*8
#define WMAP_OP 448 // padded to 7*64
#define C2K  64

#define AS1 __attribute__((address_space(1)))
#define AS3 __attribute__((address_space(3)))

typedef __attribute__((ext_vector_type(8))) short bf16x8;
typedef __attribute__((ext_vector_type(4))) float f32x4;

__device__ __forceinline__ short f2bf(float f) {
    unsigned u = __builtin_bit_cast(unsigned, f);
    u += 0x7fff + ((u >> 16) & 1);   // RNE
    return (short)(u >> 16);
}
__device__ __forceinline__ float bf2f(unsigned short u) {
    unsigned v = (unsigned)u << 16;
    return __builtin_bit_cast(float, v);
}

// ---------------------------------------------------------------- fused prep:
// blocks 0..1023:    transpose x -> XT bf16 [b][hw][c]
// blocks 1024..2559: lift weights -> Wb bf16 [768][512]
// blocks 2560..2671: c2 pad -> c2wb bf16 [448][64], c2bp f32 [448]
// block  2672:       zero gnstat (512 groups x {s, sq})
__global__ __launch_bounds__(256) void prep_kernel(
    const float* __restrict__ x, const float* __restrict__ v_w,
    const float* __restrict__ c1_w, const float* __restrict__ c2_w,
    const float* __restrict__ c2_b,
    short* __restrict__ XT, short* __restrict__ Wb,
    short* __restrict__ c2wb, float* __restrict__ c2bp,
    float* __restrict__ gnstat)
{
    __shared__ short t[64][66];
    int bx = blockIdx.x, tid = threadIdx.x;
    if (bx < 1024) {
        int b = bx >> 7, c0 = ((bx >> 4) & 7) * 64, n0 = (bx & 15) * 64;
        const float* xb = x + ((size_t)b * KDIM + c0) * HW + n0;
        #pragma unroll
        for (int l = 0; l < 16; ++l) {
            int flat = l * 256 + tid;
            int row = flat >> 6, col = flat & 63;
            t[col][row] = f2bf(xb[(size_t)row * HW + col]);
        }
        __syncthreads();
        short* xt = XT + ((size_t)b * HW + n0) * KDIM + c0;
        #pragma unroll
        for (int l = 0; l < 8; ++l) {
            int u = l * 256 + tid;
            int nrow = u >> 5, cp = (u & 31) * 2;
            short2 v = make_short2(t[nrow][cp], t[nrow][cp + 1]);
            *(short2*)(xt + (size_t)nrow * KDIM + cp) = v;
        }
    } else if (bx < 2560) {
        int idx = (bx - 1024) * 256 + tid;     // < 768*512 exactly
        int row = idx >> 9, col = idx & 511;
        int i = col >> 2, s = col & 3;
        float val;
        if (row < 256) {
            int o = row >> 2, r = row & 3;
            val = c1_w[(o * CIN + i) * 4 + ((s - r) & 3)];
        } else {
            int ro = row - 256;
            int o = ro >> 2, r = ro & 3;
            val = v_w[(o * CIN + i) * 4 + ((s - r) & 3)];
        }
        Wb[idx] = f2bf(val);
    } else if (bx < 2672) {
        int idx = (bx - 2560) * 256 + tid;     // < 448*64 exactly
        int o = idx >> 6, k = idx & 63;
        c2wb[idx] = f2bf(o < WMAP_O ? c2_w[o * C2K + k] : 0.f);
        if (idx < WMAP_OP)
            c2bp[idx] = idx < WMAP_O ? c2_b[idx] : 0.f;
    } else {
        *(float4*)(gnstat + tid * 4) = make_float4(0.f, 0.f, 0.f, 0.f);
    }
}

// ---------------------------------------------------------------- MFMA GEMM (2-phase dbuf):
// tvb[b] = bf16( Wb @ X[b] ), + GN partial stats
#define GBM 64
#define GBN 128
#define GBK 64
__global__ __launch_bounds__(256) void gemm_mfma_kernel(
    const short* __restrict__ Wb, const short* __restrict__ XT,
    short* __restrict__ tvb, float* __restrict__ gnstat)
{
    __shared__ short As[2][GBM * GBK];   // 2 x  8 KB
    __shared__ short Bs[2][GBN * GBK];   // 2 x 16 KB
    int b  = blockIdx.z;
    int m0 = blockIdx.y * GBM;
    int n0 = blockIdx.x * GBN;
    int tid = threadIdx.x;
    int lane = tid & 63, wv = tid >> 6;
    int wm = wv & 1, wn = wv >> 1;          // wave tile: 32 rows x 64 cols
    int rl = lane & 15, kg = lane >> 4;
    const short* Ab = Wb + (size_t)m0 * KDIM;
    const short* Bb = XT + ((size_t)b * HW + n0) * KDIM;
    f32x4 acc[2][4] = {};

#define GEMM_STAGE(buf, k0)                                                              \
    do {                                                                                 \
        _Pragma("unroll")                                                                \
        for (int l = 0; l < 2; ++l) {                                                    \
            int c = l * 256 + tid;                                                       \
            int row = c >> 3, kc = c & 7;                                                \
            int kcs = kc ^ (row & 7);                                                    \
            __builtin_amdgcn_global_load_lds(                                            \
                (const AS1 void*)(Ab + (size_t)row * KDIM + (k0) + kcs * 8),             \
                (AS3 void*)(As[buf] + (l * 256 + wv * 64) * 8), 16, 0, 0);               \
        }                                                                                \
        _Pragma("unroll")                                                                \
        for (int l = 0; l < 4; ++l) {                                                    \
            int c = l * 256 + tid;                                                       \
            int row = c >> 3, kc = c & 7;                                                \
            int kcs = kc ^ (row & 7);                                                    \
            __builtin_amdgcn_global_load_lds(                                            \
                (const AS1 void*)(Bb + (size_t)row * KDIM + (k0) + kcs * 8),             \
                (AS3 void*)(Bs[buf] + (l * 256 + wv * 64) * 8), 16, 0, 0);               \
        }                                                                                \
    } while (0)

    GEMM_STAGE(0, 0);
    __syncthreads();
    for (int t = 0; t < KDIM / GBK; ++t) {
        int cur = t & 1;
        if (t < KDIM / GBK - 1) GEMM_STAGE(cur ^ 1, (t + 1) * GBK);
        #pragma unroll
        for (int ks = 0; ks < 2; ++ks) {
            bf16x8 af[2], bfr[4];
            #pragma unroll
            for (int mf = 0; mf < 2; ++mf) {
                int row = wm * 32 + mf * 16 + rl;
                af[mf] = *(const bf16x8*)(As[cur] + row * GBK + ((ks * 4 + kg) ^ (row & 7)) * 8);
            }
            #pragma unroll
            for (int nf = 0; nf < 4; ++nf) {
                int row = wn * 64 + nf * 16 + rl;
                bfr[nf] = *(const bf16x8*)(Bs[cur] + row * GBK + ((ks * 4 + kg) ^ (row & 7)) * 8);
            }
            #pragma unroll
            for (int mf = 0; mf < 2; ++mf)
                #pragma unroll
                for (int nf = 0; nf < 4; ++nf)
                    acc[mf][nf] = __builtin_amdgcn_mfma_f32_16x16x32_bf16(af[mf], bfr[nf], acc[mf][nf], 0, 0, 0);
        }
        __syncthreads();
    }
#undef GEMM_STAGE

    short* Cb = tvb + (size_t)b * MROWS * HW;
    #pragma unroll
    for (int mf = 0; mf < 2; ++mf) {
        int rowb = m0 + wm * 32 + mf * 16 + kg * 4;
        #pragma unroll
        for (int nf = 0; nf < 4; ++nf) {
            int col = n0 + wn * 64 + nf * 16 + rl;
            #pragma unroll
            for (int i = 0; i < 4; ++i)
                Cb[(size_t)(rowb + i) * HW + col] = f2bf(acc[mf][nf][i]);
        }
    }

    // GN partial stats for t rows: each (wave,mf) covers one 4-row group x 64 cols
    if (m0 < TROWS) {
        #pragma unroll
        for (int mf = 0; mf < 2; ++mf) {
            float s = 0.f, sq = 0.f;
            #pragma unroll
            for (int nf = 0; nf < 4; ++nf)
                #pragma unroll
                for (int i = 0; i < 4; ++i) {
                    float v = acc[mf][nf][i];
                    s += v; sq += v * v;
                }
            #pragma unroll
            for (int m = 1; m <= 8; m <<= 1) {
                s  += __shfl_xor(s, m);
                sq += __shfl_xor(sq, m);
            }
            if (rl == 0) {
                int grp = (m0 + wm * 32 + mf * 16 + kg * 4) >> 2;
                atomicAdd(&gnstat[(b * 64 + grp) * 2],     s);
                atomicAdd(&gnstat[(b * 64 + grp) * 2 + 1], sq);
            }
        }
    }
}

// ---------------------------------------------------------------- tkn2: normalize + affine + relu + transpose
__global__ __launch_bounds__(256) void tkn2_kernel(
    const short* __restrict__ tvb, const float* __restrict__ gnstat,
    const float* __restrict__ gn_g, const float* __restrict__ gn_b,
    short* __restrict__ tn)
{
    __shared__ short ts[64][72];
    __shared__ float sc[64], sh[64];
    int b4r = blockIdx.x;
    int b = b4r >> 2, r = b4r & 3;
    int hw0 = blockIdx.y * 64;
    int tid = threadIdx.x;
    if (tid < 64) {
        float s   = gnstat[(b * 64 + tid) * 2];
        float sq  = gnstat[(b * 64 + tid) * 2 + 1];
        float mu  = s * (1.f / 4096.f);
        float var = sq * (1.f / 4096.f) - mu * mu;
        float inv = rsqrtf(var + 1e-5f);
        int ch = tid * 4 + r;
        float g = gn_g[ch], bb = gn_b[ch];
        sc[tid] = inv * g;
        sh[tid] = bb - mu * inv * g;
    }
    #pragma unroll
    for (int l = 0; l < 16; ++l) {
        int flat = l * 256 + tid;
        int c = flat >> 6, hw = flat & 63;
        ts[c][hw] = tvb[((size_t)b * MROWS + c * 4 + r) * HW + hw0 + hw];
    }
    __syncthreads();
    #pragma unroll
    for (int l = 0; l < 2; ++l) {
        int u = l * 256 + tid;
        int hw = u >> 3, c0 = (u & 7) * 8;
        bf16x8 v;
        #pragma unroll
        for (int j = 0; j < 8; ++j) {
            float f = bf2f((unsigned short)ts[c0 + j][hw]);
            f = fmaxf(f * sc[c0 + j] + sh[c0 + j], 0.f);
            v[j] = f2bf(f);
        }
        *(bf16x8*)(tn + ((size_t)b4r * HW + hw0 + hw) * C2K + c0) = v;
    }
}

// ---------------------------------------------------------------- wagg: fused wmap-MFMA + aggregation
// grid (32, 32): x = strip*8 + g, y = b4r. Per block:
//   P[64 o][256 px] = c2wb[g*49..] @ tn[b4r, strip]  (MFMA, bias, bf16 -> LDS)
//   out[b, (g,cc,r), strip] = sum_p P[rot(p)] * v_halo
// LDS: As 8K + Bs 32K (P 33.8K aliases them) | vt bf16 21.1K => 62.1 KB, 2 blocks/CU
__global__ __launch_bounds__(256) void wagg_kernel(
    const short* __restrict__ c2wb, const short* __restrict__ tn,
    const float* __restrict__ c2bp, const short* __restrict__ tvb,
    float* __restrict__ out)
{
    __shared__ char smem[62080];
    short* As_ = (short*)smem;                       // [64][64]
    short* Bs_ = (short*)(smem + 8192);              // [256][64]
    short* P   = (short*)smem;                       // [64][264], alias after barrier
    unsigned short* vt = (unsigned short*)(smem + 40960);  // [16][15][44] bf16

    int g = blockIdx.x & 7, s = blockIdx.x >> 3;
    int b4r = blockIdx.y;
    int b = b4r >> 2, r = b4r & 3;
    int h0 = s * 8;
    int tid = threadIdx.x;
    int lane = tid & 63, wv = tid >> 6;
    int rl = lane & 15, kg = lane >> 4;

    // stage A: 64 rows of c2wb from row g*49 (max 406 < 448)
    #pragma unroll
    for (int l = 0; l < 2; ++l) {
        int c = l * 256 + tid;
        int row = c >> 3, kc = c & 7;
        int kcs = kc ^ (row & 7);
        __builtin_amdgcn_global_load_lds(
            (const AS1 void*)(c2wb + (size_t)(g * 49 + row) * C2K + kcs * 8),
            (AS3 void*)(As_ + (l * 256 + wv * 64) * 8), 16, 0, 0);
    }
    // stage B: 256 rows of tn starting at b4r*1024 + s*256
    const short* Bb = tn + ((size_t)b4r * HW + s * 256) * C2K;
    #pragma unroll
    for (int l = 0; l < 8; ++l) {
        int c = l * 256 + tid;
        int row = c >> 3, kc = c & 7;
        int kcs = kc ^ (row & 7);
        __builtin_amdgcn_global_load_lds(
            (const AS1 void*)(Bb + (size_t)row * C2K + kcs * 8),
            (AS3 void*)(Bs_ + (l * 256 + wv * 64) * 8), 16, 0, 0);
    }
    // stage v halo (bf16), overlapped with A/B staging
    {
        const short* vpb = tvb + ((size_t)b * MROWS + TROWS) * HW;
        for (int e = tid; e < 16 * 15 * 3; e += 256) {
            int cc = e / 45; int rem = e - cc * 45;
            int row = rem / 3, q = rem - row * 3;
            int col = (q == 0) ? 0 : (36 + (q - 1) * 4);
            ushort4 z = {0, 0, 0, 0};
            *(ushort4*)(&vt[(cc * 15 + row) * 44 + col]) = z;
        }
        for (int f = tid; f < 16 * 15 * 8; f += 256) {
            int cc = f / 120; int rem = f - cc * 120;
            int row = rem >> 3, q = rem & 7;
            int gh = h0 - 3 + row;
            ushort4 u = {0, 0, 0, 0};
            if (gh >= 0 && gh < HH) {
                int ch = (g * GC + cc) * 4 + r;
                u = *(const ushort4*)(vpb + (size_t)ch * HW + gh * WWID + q * 4);
            }
            *(ushort4*)(&vt[(cc * 15 + row) * 44 + 4 + q * 4]) = u;
        }
    }
    __syncthreads();

    // MFMA: M=64 (o), N=256 (px); wave wv owns cols wv*64..wv*64+63
    f32x4 acc[4][4] = {};
    #pragma unroll
    for (int ks = 0; ks < 2; ++ks) {
        bf16x8 af[4], bfr[4];
        #pragma unroll
        for (int mf = 0; mf < 4; ++mf) {
            int row = mf * 16 + rl;
            af[mf] = *(const bf16x8*)(As_ + row * C2K + ((ks * 4 + kg) ^ (row & 7)) * 8);
        }
        #pragma unroll
        for (int nf = 0; nf < 4; ++nf) {
            int row = wv * 64 + nf * 16 + rl;
            bfr[nf] = *(const bf16x8*)(Bs_ + row * C2K + ((ks * 4 + kg) ^ (row & 7)) * 8);
        }
        #pragma unroll
        for (int mf = 0; mf < 4; ++mf)
            #pragma unroll
            for (int nf = 0; nf < 4; ++nf)
                acc[mf][nf] = __builtin_amdgcn_mfma_f32_16x16x32_bf16(af[mf], bfr[nf], acc[mf][nf], 0, 0, 0);
    }
    __syncthreads();   // all frag reads done -> safe to overwrite As_/Bs_ via P

    // P write: bias + bf16; P[row][col], row=o (0..63), col=px (0..255), pitch 264
    #pragma unroll
    for (int mf = 0; mf < 4; ++mf) {
        int rowb = mf * 16 + kg * 4;
        float bi[4];
        #pragma unroll
        for (int i = 0; i < 4; ++i) bi[i] = c2bp[g * 49 + rowb + i];
        #pragma unroll
        for (int nf = 0; nf < 4; ++nf) {
            int col = wv * 64 + nf * 16 + rl;
            #pragma unroll
            for (int i = 0; i < 4; ++i)
                P[(rowb + i) * 264 + col] = f2bf(acc[mf][nf][i] + bi[i]);
        }
    }
    __syncthreads();

    // aggregation (agg5 inner loop, weights from P, v from bf16 vt)
    int w0q = tid & 7, hb = (tid >> 3) & 1, cc4 = (tid >> 4) & 3, cq = tid >> 6;
    int hl = cq * 2 + hb;
    int h = h0 + hl, w0 = w0q * 4;

    int A_, Bc, Cc;
    if      (r == 0) { A_ = 0;  Bc = 7;  Cc = 1;  }
    else if (r == 1) { A_ = 6;  Bc = -1; Cc = 7;  }
    else if (r == 2) { A_ = 48; Bc = -7; Cc = -1; }
    else             { A_ = 42; Bc = 1;  Cc = -7; }

    float acc2[4][4] = {};
    #pragma unroll
    for (int di = 0; di < 7; ++di) {
        float wrf[7][4];
        #pragma unroll
        for (int dj = 0; dj < 7; ++dj) {
            int porig = A_ + Bc * di + Cc * dj;
            ushort4 wv4 = *(const ushort4*)(&P[porig * 264 + hl * 32 + w0]);
            wrf[dj][0] = bf2f(wv4.x); wrf[dj][1] = bf2f(wv4.y);
            wrf[dj][2] = bf2f(wv4.z); wrf[dj][3] = bf2f(wv4.w);
        }
        #pragma unroll
        for (int c2 = 0; c2 < 4; ++c2) {
            int hc = cc4 * 4 + c2;
            const unsigned short* rp = &vt[(hc * 15 + hl + di) * 44 + w0];
            ushort4 a0 = *(const ushort4*)(rp);
            ushort4 a1 = *(const ushort4*)(rp + 4);
            ushort4 a2 = *(const ushort4*)(rp + 8);
            float win[12] = {bf2f(a0.x), bf2f(a0.y), bf2f(a0.z), bf2f(a0.w),
                             bf2f(a1.x), bf2f(a1.y), bf2f(a1.z), bf2f(a1.w),
                             bf2f(a2.x), bf2f(a2.y), bf2f(a2.z), bf2f(a2.w)};
            #pragma unroll
            for (int dj = 0; dj < 7; ++dj)
                #pragma unroll
                for (int px = 0; px < 4; ++px)
                    acc2[c2][px] += wrf[dj][px] * win[px + dj + 1];
        }
    }
    #pragma unroll
    for (int c2 = 0; c2 < 4; ++c2) {
        int ch = (g * GC + cc4 * 4 + c2) * 4 + r;
        float4 o4 = make_float4(acc2[c2][0], acc2[c2][1], acc2[c2][2], acc2[c2][3]);
        *(float4*)(out + ((size_t)b * 512 + ch) * HW + h * WWID + w0) = o4;
    }
}

// ---------------------------------------------------------------- launch
extern "C" void kernel_launch(void* const* d_in, const int* in_sizes, int n_in,
                              void* d_out, int out_size, void* d_ws, size_t ws_size,
                              hipStream_t stream)
{
    const float* x    = (const float*)d_in[0];
    const float* v_w  = (const float*)d_in[1];
    const float* c1_w = (const float*)d_in[2];
    const float* gn_g = (const float*)d_in[3];
    const float* gn_b = (const float*)d_in[4];
    const float* c2_w = (const float*)d_in[5];
    const float* c2_b = (const float*)d_in[6];
    float* out = (float*)d_out;

    char* p = (char*)d_ws;
    short* Wb     = (short*)p;           p += (size_t)MROWS * KDIM * 2;        //  0.79 MB
    short* tvb    = (short*)p;           p += (size_t)BB * MROWS * HW * 2;     // 12.6 MB
    short* XT     = (short*)p;           p += (size_t)BB * HW * KDIM * 2;      //  8.4 MB
    short* tn     = (short*)p;           p += (size_t)32 * HW * C2K * 2;       //  4.2 MB
    short* c2wb   = (short*)p;           p += (size_t)WMAP_OP * C2K * 2;       // 57 KB
    float* c2bp   = (float*)p;           p += (size_t)WMAP_OP * 4;
    float* gnstat = (float*)p;           p += (size_t)512 * 2 * 4;             //  4 KB

    prep_kernel     <<<2673, 256, 0, stream>>>(x, v_w, c1_w, c2_w, c2_b, XT, Wb, c2wb, c2bp, gnstat);
    gemm_mfma_kernel<<<dim3(HW / GBN, MROWS / GBM, BB), 256, 0, stream>>>(Wb, XT, tvb, gnstat);
    tkn2_kernel     <<<dim3(32, 16), 256, 0, stream>>>(tvb, gnstat, gn_g, gn_b, tn);
    wagg_kernel     <<<dim3(32, 32), 256, 0, stream>>>(c2wb, tn, c2bp, tvb, out);
}

// Round 10
// 64.333 us; speedup vs baseline: 1.3283x; 1.3283x over previous
//
#include <hip/hip_runtime.h>

// Problem constants
#define BB   8
#define CIN  128
#define COUT 128
#define KS   7
#define HH   32
#define WWID 32
#define HW   1024
#define NG   8     // dynamic-weight groups
#define GC   16    // channels per group
#define MROWS 768  // 256 t-rows + 512 v-rows
#define TROWS 256
#define VROWS 512
#define KDIM 512
#define WMAP_O 392  // 49*8
#define WMAP_OP 448 // padded to 7*64
#define C2K  64

#define AS1 __attribute__((address_space(1)))
#define AS3 __attribute__((address_space(3)))

typedef __attribute__((ext_vector_type(8))) short bf16x8;
typedef __attribute__((ext_vector_type(4))) float f32x4;

__device__ __forceinline__ short f2bf(float f) {
    unsigned u = __builtin_bit_cast(unsigned, f);
    u += 0x7fff + ((u >> 16) & 1);   // RNE
    return (short)(u >> 16);
}
__device__ __forceinline__ float bf2f(unsigned short u) {
    unsigned v = (unsigned)u << 16;
    return __builtin_bit_cast(float, v);
}

// ---------------------------------------------------------------- fused prep:
// blocks 0..1023:    transpose x -> XT bf16 [b][hw][c]
// blocks 1024..2559: lift weights -> Wb bf16 [768][512]
// blocks 2560..2671: c2 pad -> c2wb bf16 [448][64], c2bp f32 [448]
// block  2672:       zero gnstat (512 groups x {s, sq})
__global__ __launch_bounds__(256) void prep_kernel(
    const float* __restrict__ x, const float* __restrict__ v_w,
    const float* __restrict__ c1_w, const float* __restrict__ c2_w,
    const float* __restrict__ c2_b,
    short* __restrict__ XT, short* __restrict__ Wb,
    short* __restrict__ c2wb, float* __restrict__ c2bp,
    float* __restrict__ gnstat)
{
    __shared__ short t[64][66];
    int bx = blockIdx.x, tid = threadIdx.x;
    if (bx < 1024) {
        int b = bx >> 7, c0 = ((bx >> 4) & 7) * 64, n0 = (bx & 15) * 64;
        const float* xb = x + ((size_t)b * KDIM + c0) * HW + n0;
        #pragma unroll
        for (int l = 0; l < 16; ++l) {
            int flat = l * 256 + tid;
            int row = flat >> 6, col = flat & 63;
            t[col][row] = f2bf(xb[(size_t)row * HW + col]);
        }
        __syncthreads();
        short* xt = XT + ((size_t)b * HW + n0) * KDIM + c0;
        #pragma unroll
        for (int l = 0; l < 8; ++l) {
            int u = l * 256 + tid;
            int nrow = u >> 5, cp = (u & 31) * 2;
            short2 v = make_short2(t[nrow][cp], t[nrow][cp + 1]);
            *(short2*)(xt + (size_t)nrow * KDIM + cp) = v;
        }
    } else if (bx < 2560) {
        int idx = (bx - 1024) * 256 + tid;     // < 768*512 exactly
        int row = idx >> 9, col = idx & 511;
        int i = col >> 2, s = col & 3;
        float val;
        if (row < 256) {
            int o = row >> 2, r = row & 3;
            val = c1_w[(o * CIN + i) * 4 + ((s - r) & 3)];
        } else {
            int ro = row - 256;
            int o = ro >> 2, r = ro & 3;
            val = v_w[(o * CIN + i) * 4 + ((s - r) & 3)];
        }
        Wb[idx] = f2bf(val);
    } else if (bx < 2672) {
        int idx = (bx - 2560) * 256 + tid;     // < 448*64 exactly
        int o = idx >> 6, k = idx & 63;
        c2wb[idx] = f2bf(o < WMAP_O ? c2_w[o * C2K + k] : 0.f);
        if (idx < WMAP_OP)
            c2bp[idx] = idx < WMAP_O ? c2_b[idx] : 0.f;
    } else {
        *(float4*)(gnstat + tid * 4) = make_float4(0.f, 0.f, 0.f, 0.f);
    }
}

// ---------------------------------------------------------------- MFMA GEMM (2-phase dbuf):
// tvb[b] = bf16( Wb @ X[b] ), + GN partial stats
#define GBM 64
#define GBN 128
#define GBK 64
__global__ __launch_bounds__(256) void gemm_mfma_kernel(
    const short* __restrict__ Wb, const short* __restrict__ XT,
    short* __restrict__ tvb, float* __restrict__ gnstat)
{
    __shared__ short As[2][GBM * GBK];   // 2 x  8 KB
    __shared__ short Bs[2][GBN * GBK];   // 2 x 16 KB
    int b  = blockIdx.z;
    int m0 = blockIdx.y * GBM;
    int n0 = blockIdx.x * GBN;
    int tid = threadIdx.x;
    int lane = tid & 63, wv = tid >> 6;
    int wm = wv & 1, wn = wv >> 1;          // wave tile: 32 rows x 64 cols
    int rl = lane & 15, kg = lane >> 4;
    const short* Ab = Wb + (size_t)m0 * KDIM;
    const short* Bb = XT + ((size_t)b * HW + n0) * KDIM;
    f32x4 acc[2][4] = {};

#define GEMM_STAGE(buf, k0)                                                              \
    do {                                                                                 \
        _Pragma("unroll")                                                                \
        for (int l = 0; l < 2; ++l) {                                                    \
            int c = l * 256 + tid;                                                       \
            int row = c >> 3, kc = c & 7;                                                \
            int kcs = kc ^ (row & 7);                                                    \
            __builtin_amdgcn_global_load_lds(                                            \
                (const AS1 void*)(Ab + (size_t)row * KDIM + (k0) + kcs * 8),             \
                (AS3 void*)(As[buf] + (l * 256 + wv * 64) * 8), 16, 0, 0);               \
        }                                                                                \
        _Pragma("unroll")                                                                \
        for (int l = 0; l < 4; ++l) {                                                    \
            int c = l * 256 + tid;                                                       \
            int row = c >> 3, kc = c & 7;                                                \
            int kcs = kc ^ (row & 7);                                                    \
            __builtin_amdgcn_global_load_lds(                                            \
                (const AS1 void*)(Bb + (size_t)row * KDIM + (k0) + kcs * 8),             \
                (AS3 void*)(Bs[buf] + (l * 256 + wv * 64) * 8), 16, 0, 0);               \
        }                                                                                \
    } while (0)

    GEMM_STAGE(0, 0);
    __syncthreads();
    for (int t = 0; t < KDIM / GBK; ++t) {
        int cur = t & 1;
        if (t < KDIM / GBK - 1) GEMM_STAGE(cur ^ 1, (t + 1) * GBK);
        #pragma unroll
        for (int ks = 0; ks < 2; ++ks) {
            bf16x8 af[2], bfr[4];
            #pragma unroll
            for (int mf = 0; mf < 2; ++mf) {
                int row = wm * 32 + mf * 16 + rl;
                af[mf] = *(const bf16x8*)(As[cur] + row * GBK + ((ks * 4 + kg) ^ (row & 7)) * 8);
            }
            #pragma unroll
            for (int nf = 0; nf < 4; ++nf) {
                int row = wn * 64 + nf * 16 + rl;
                bfr[nf] = *(const bf16x8*)(Bs[cur] + row * GBK + ((ks * 4 + kg) ^ (row & 7)) * 8);
            }
            #pragma unroll
            for (int mf = 0; mf < 2; ++mf)
                #pragma unroll
                for (int nf = 0; nf < 4; ++nf)
                    acc[mf][nf] = __builtin_amdgcn_mfma_f32_16x16x32_bf16(af[mf], bfr[nf], acc[mf][nf], 0, 0, 0);
        }
        __syncthreads();
    }
#undef GEMM_STAGE

    short* Cb = tvb + (size_t)b * MROWS * HW;
    #pragma unroll
    for (int mf = 0; mf < 2; ++mf) {
        int rowb = m0 + wm * 32 + mf * 16 + kg * 4;
        #pragma unroll
        for (int nf = 0; nf < 4; ++nf) {
            int col = n0 + wn * 64 + nf * 16 + rl;
            #pragma unroll
            for (int i = 0; i < 4; ++i)
                Cb[(size_t)(rowb + i) * HW + col] = f2bf(acc[mf][nf][i]);
        }
    }

    // GN partial stats for t rows: each (wave,mf) covers one 4-row group x 64 cols
    if (m0 < TROWS) {
        #pragma unroll
        for (int mf = 0; mf < 2; ++mf) {
            float s = 0.f, sq = 0.f;
            #pragma unroll
            for (int nf = 0; nf < 4; ++nf)
                #pragma unroll
                for (int i = 0; i < 4; ++i) {
                    float v = acc[mf][nf][i];
                    s += v; sq += v * v;
                }
            #pragma unroll
            for (int m = 1; m <= 8; m <<= 1) {
                s  += __shfl_xor(s, m);
                sq += __shfl_xor(sq, m);
            }
            if (rl == 0) {
                int grp = (m0 + wm * 32 + mf * 16 + kg * 4) >> 2;
                atomicAdd(&gnstat[(b * 64 + grp) * 2],     s);
                atomicAdd(&gnstat[(b * 64 + grp) * 2 + 1], sq);
            }
        }
    }
}

// ---------------------------------------------------------------- tkn2: normalize + affine + relu + transpose
__global__ __launch_bounds__(256) void tkn2_kernel(
    const short* __restrict__ tvb, const float* __restrict__ gnstat,
    const float* __restrict__ gn_g, const float* __restrict__ gn_b,
    short* __restrict__ tn)
{
    __shared__ short ts[64][72];
    __shared__ float sc[64], sh[64];
    int b4r = blockIdx.x;
    int b = b4r >> 2, r = b4r & 3;
    int hw0 = blockIdx.y * 64;
    int tid = threadIdx.x;
    if (tid < 64) {
        float s   = gnstat[(b * 64 + tid) * 2];
        float sq  = gnstat[(b * 64 + tid) * 2 + 1];
        float mu  = s * (1.f / 4096.f);
        float var = sq * (1.f / 4096.f) - mu * mu;
        float inv = rsqrtf(var + 1e-5f);
        int ch = tid * 4 + r;
        float g = gn_g[ch], bb = gn_b[ch];
        sc[tid] = inv * g;
        sh[tid] = bb - mu * inv * g;
    }
    #pragma unroll
    for (int l = 0; l < 16; ++l) {
        int flat = l * 256 + tid;
        int c = flat >> 6, hw = flat & 63;
        ts[c][hw] = tvb[((size_t)b * MROWS + c * 4 + r) * HW + hw0 + hw];
    }
    __syncthreads();
    #pragma unroll
    for (int l = 0; l < 2; ++l) {
        int u = l * 256 + tid;
        int hw = u >> 3, c0 = (u & 7) * 8;
        bf16x8 v;
        #pragma unroll
        for (int j = 0; j < 8; ++j) {
            float f = bf2f((unsigned short)ts[c0 + j][hw]);
            f = fmaxf(f * sc[c0 + j] + sh[c0 + j], 0.f);
            v[j] = f2bf(f);
        }
        *(bf16x8*)(tn + ((size_t)b4r * HW + hw0 + hw) * C2K + c0) = v;
    }
}

// ---------------------------------------------------------------- wmap v3: MFMA GEMM, bf16 out
// wmapB[b4r][o][hw] = bf16( c2bp[o] + sum_c c2wb[o][c] * tn[b4r][hw][c] )
__global__ __launch_bounds__(256) void wmap3_kernel(
    const short* __restrict__ c2wb, const short* __restrict__ tn,
    const float* __restrict__ c2bp, short* __restrict__ wmapB)
{
    __shared__ short As[64 * 64];    // 8 KB
    __shared__ short Bs[128 * 64];   // 16 KB
    int n0  = blockIdx.x * 128;
    int m0  = blockIdx.y * 64;
    int b4r = blockIdx.z;
    int tid = threadIdx.x;
    int lane = tid & 63, wv = tid >> 6;
    int wm = wv & 1, wn = wv >> 1;
    int rl = lane & 15, kg = lane >> 4;
    const short* Bb = tn + ((size_t)b4r * HW + n0) * C2K;

    #pragma unroll
    for (int l = 0; l < 2; ++l) {
        int c = l * 256 + tid;
        int row = c >> 3, kc = c & 7;
        int kcs = kc ^ (row & 7);
        __builtin_amdgcn_global_load_lds(
            (const AS1 void*)(c2wb + (size_t)(m0 + row) * C2K + kcs * 8),
            (AS3 void*)(As + (l * 256 + wv * 64) * 8), 16, 0, 0);
    }
    #pragma unroll
    for (int l = 0; l < 4; ++l) {
        int c = l * 256 + tid;
        int row = c >> 3, kc = c & 7;
        int kcs = kc ^ (row & 7);
        __builtin_amdgcn_global_load_lds(
            (const AS1 void*)(Bb + (size_t)row * C2K + kcs * 8),
            (AS3 void*)(Bs + (l * 256 + wv * 64) * 8), 16, 0, 0);
    }
    __syncthreads();

    f32x4 acc[2][4] = {};
    #pragma unroll
    for (int ks = 0; ks < 2; ++ks) {
        bf16x8 af[2], bfr[4];
        #pragma unroll
        for (int mf = 0; mf < 2; ++mf) {
            int row = wm * 32 + mf * 16 + rl;
            af[mf] = *(const bf16x8*)(As + row * 64 + ((ks * 4 + kg) ^ (row & 7)) * 8);
        }
        #pragma unroll
        for (int nf = 0; nf < 4; ++nf) {
            int row = wn * 64 + nf * 16 + rl;
            bfr[nf] = *(const bf16x8*)(Bs + row * 64 + ((ks * 4 + kg) ^ (row & 7)) * 8);
        }
        #pragma unroll
        for (int mf = 0; mf < 2; ++mf)
            #pragma unroll
            for (int nf = 0; nf < 4; ++nf)
                acc[mf][nf] = __builtin_amdgcn_mfma_f32_16x16x32_bf16(af[mf], bfr[nf], acc[mf][nf], 0, 0, 0);
    }

    short* wb = wmapB + (size_t)b4r * WMAP_OP * HW;
    #pragma unroll
    for (int mf = 0; mf < 2; ++mf) {
        int rowb = m0 + wm * 32 + mf * 16 + kg * 4;
        float bi[4];
        #pragma unroll
        for (int i = 0; i < 4; ++i) bi[i] = c2bp[rowb + i];
        #pragma unroll
        for (int nf = 0; nf < 4; ++nf) {
            int col = n0 + wn * 64 + nf * 16 + rl;
            #pragma unroll
            for (int i = 0; i < 4; ++i)
                wb[(size_t)(rowb + i) * HW + col] = f2bf(acc[mf][nf][i] + bi[i]);
        }
    }
}

// ---------------------------------------------------------------- aggregation v5 (merged c-halves)
// grid: (256 bgr, 4 h-strips); block: 16 ch x 8 h x 32 w
// lane map: w0q = tid&7, hb = (tid>>3)&1, cc4 = (tid>>4)&3, cq = wave
// weights loaded once per (di,dj), reused for 4 channels per lane
__global__ __launch_bounds__(256, 3) void agg5_kernel(
    const short* __restrict__ tvb, const short* __restrict__ wmapB,
    float* __restrict__ out)
{
    __shared__ float vt[16][15][44];  // 42.2 KB
    int bx = blockIdx.x;              // b*32 + g*4 + r
    int b = bx >> 5;
    int g = (bx >> 2) & 7;
    int r = bx & 3;
    int h0  = blockIdx.y * 8;
    int tid = threadIdx.x;
    int w0q = tid & 7, hb = (tid >> 3) & 1, cc4 = (tid >> 4) & 3, cq = tid >> 6;
    int hl = cq * 2 + hb;             // local h 0..7
    int h = h0 + hl, w0 = w0q * 4;

    int A, Bc, Cc;
    if      (r == 0) { A = 0;  Bc = 7;  Cc = 1;  }
    else if (r == 1) { A = 6;  Bc = -1; Cc = 7;  }
    else if (r == 2) { A = 48; Bc = -7; Cc = -1; }
    else             { A = 42; Bc = 1;  Cc = -7; }

    const short* vpb = tvb + ((size_t)b * MROWS + TROWS) * HW;
    // edge quads (cols 0..3, 36..43) are always out of image -> zero
    for (int e = tid; e < 16 * 15 * 3; e += 256) {
        int cc  = e / 45;
        int rem = e - cc * 45;
        int row = rem / 3, q = rem - row * 3;
        int col = (q == 0) ? 0 : (36 + (q - 1) * 4);
        *(float4*)(&vt[cc][row][col]) = make_float4(0.f, 0.f, 0.f, 0.f);
    }
    // interior quads: cols 4..35 <-> gw 0..31 (aligned ushort4)
    for (int f = tid; f < 16 * 15 * 8; f += 256) {
        int cc  = f / 120;
        int rem = f - cc * 120;
        int row = rem >> 3, q = rem & 7;
        int gh = h0 - 3 + row;
        float4 v4 = make_float4(0.f, 0.f, 0.f, 0.f);
        if (gh >= 0 && gh < HH) {
            int ch = (g * GC + cc) * 4 + r;
            ushort4 u = *(const ushort4*)(vpb + (size_t)ch * HW + gh * WWID + q * 4);
            v4 = make_float4(bf2f(u.x), bf2f(u.y), bf2f(u.z), bf2f(u.w));
        }
        *(float4*)(&vt[cc][row][4 + q * 4]) = v4;
    }
    __syncthreads();

    const short* wmb = wmapB + ((size_t)(b * 4 + r) * WMAP_OP + g * 49) * HW + h * WWID + w0;
    float acc[4][4] = {};
    #pragma unroll
    for (int di = 0; di < 7; ++di) {
        float wrf[7][4];
        #pragma unroll
        for (int dj = 0; dj < 7; ++dj) {
            int porig = A + Bc * di + Cc * dj;
            ushort4 wv = *(const ushort4*)(wmb + (size_t)porig * HW);
            wrf[dj][0] = bf2f(wv.x); wrf[dj][1] = bf2f(wv.y);
            wrf[dj][2] = bf2f(wv.z); wrf[dj][3] = bf2f(wv.w);
        }
        #pragma unroll
        for (int c2 = 0; c2 < 4; ++c2) {
            int hc = cc4 * 4 + c2;
            const float* rp = &vt[hc][hl + di][w0];
            float4 q0 = *(const float4*)(rp);
            float4 q1 = *(const float4*)(rp + 4);
            float4 q2 = *(const float4*)(rp + 8);
            float win[12] = {q0.x, q0.y, q0.z, q0.w,
                             q1.x, q1.y, q1.z, q1.w,
                             q2.x, q2.y, q2.z, q2.w};
            #pragma unroll
            for (int dj = 0; dj < 7; ++dj)
                #pragma unroll
                for (int px = 0; px < 4; ++px)
                    acc[c2][px] += wrf[dj][px] * win[px + dj + 1];
        }
    }
    #pragma unroll
    for (int c2 = 0; c2 < 4; ++c2) {
        int ch = (g * GC + cc4 * 4 + c2) * 4 + r;
        float4 o4 = make_float4(acc[c2][0], acc[c2][1], acc[c2][2], acc[c2][3]);
        *(float4*)(out + ((size_t)b * 512 + ch) * HW + h * WWID + w0) = o4;
    }
}

// ---------------------------------------------------------------- launch
extern "C" void kernel_launch(void* const* d_in, const int* in_sizes, int n_in,
                              void* d_out, int out_size, void* d_ws, size_t ws_size,
                              hipStream_t stream)
{
    const float* x    = (const float*)d_in[0];
    const float* v_w  = (const float*)d_in[1];
    const float* c1_w = (const float*)d_in[2];
    const float* gn_g = (const float*)d_in[3];
    const float* gn_b = (const float*)d_in[4];
    const float* c2_w = (const float*)d_in[5];
    const float* c2_b = (const float*)d_in[6];
    float* out = (float*)d_out;

    // workspace layout (XT aliases wmapB; XT dead before wmapB written)
    char* p = (char*)d_ws;
    short* Wb     = (short*)p;           p += (size_t)MROWS * KDIM * 2;        //  0.79 MB
    short* tvb    = (short*)p;           p += (size_t)BB * MROWS * HW * 2;     // 12.6 MB
    short* wmapB  = (short*)p;           p += (size_t)32 * WMAP_OP * HW * 2;   // 29.4 MB
    short* XT     = (short*)wmapB;                                             //  8.4 MB (aliased)
    short* tn     = (short*)p;           p += (size_t)32 * HW * C2K * 2;       //  4.2 MB
    short* c2wb   = (short*)p;           p += (size_t)WMAP_OP * C2K * 2;       // 57 KB
    float* c2bp   = (float*)p;           p += (size_t)WMAP_OP * 4;
    float* gnstat = (float*)p;           p += (size_t)512 * 2 * 4;             //  4 KB

    prep_kernel     <<<2673, 256, 0, stream>>>(x, v_w, c1_w, c2_w, c2_b, XT, Wb, c2wb, c2bp, gnstat);
    gemm_mfma_kernel<<<dim3(HW / GBN, MROWS / GBM, BB), 256, 0, stream>>>(Wb, XT, tvb, gnstat);
    tkn2_kernel     <<<dim3(32, 16), 256, 0, stream>>>(tvb, gnstat, gn_g, gn_b, tn);
    wmap3_kernel    <<<dim3(HW / 128, WMAP_OP / 64, 32), 256, 0, stream>>>(c2wb, tn, c2bp, wmapB);
    agg5_kernel     <<<dim3(BB * NG * 4, 4), 256, 0, stream>>>(tvb, wmapB, out);
}

// Round 11
// 61.444 us; speedup vs baseline: 1.3908x; 1.0470x over previous
//
#include <hip/hip_runtime.h>

// Problem constants
#define BB   8
#define CIN  128
#define COUT 128
#define KS   7
#define HH   32
#define WWID 32
#define HW   1024
#define NG   8     // dynamic-weight groups
#define GC   16    // channels per group
#define MROWS 768  // 256 t-rows + 512 v-rows
#define TROWS 256
#define VROWS 512
#define KDIM 512
#define WMAP_O 392  // 49*8
#define WMAP_OP 448 // padded to 7*64
#define C2K  64

#define AS1 __attribute__((address_space(1)))
#define AS3 __attribute__((address_space(3)))

typedef __attribute__((ext_vector_type(8))) short bf16x8;
typedef __attribute__((ext_vector_type(4))) float f32x4;

__device__ __forceinline__ short f2bf(float f) {
    unsigned u = __builtin_bit_cast(unsigned, f);
    u += 0x7fff + ((u >> 16) & 1);   // RNE
    return (short)(u >> 16);
}
__device__ __forceinline__ float bf2f(unsigned short u) {
    unsigned v = (unsigned)u << 16;
    return __builtin_bit_cast(float, v);
}

// ---------------------------------------------------------------- fused prep:
// blocks 0..1023:    transpose x -> XT bf16 [b][hw][c]
// blocks 1024..2559: lift weights -> Wb bf16 [768][512]
// blocks 2560..2671: c2 pad -> c2wb bf16 [448][64], c2bp f32 [448]
// block  2672:       zero gnstat (512 groups x {s, sq})
__global__ __launch_bounds__(256) void prep_kernel(
    const float* __restrict__ x, const float* __restrict__ v_w,
    const float* __restrict__ c1_w, const float* __restrict__ c2_w,
    const float* __restrict__ c2_b,
    short* __restrict__ XT, short* __restrict__ Wb,
    short* __restrict__ c2wb, float* __restrict__ c2bp,
    float* __restrict__ gnstat)
{
    __shared__ short t[64][66];
    int bx = blockIdx.x, tid = threadIdx.x;
    if (bx < 1024) {
        int b = bx >> 7, c0 = ((bx >> 4) & 7) * 64, n0 = (bx & 15) * 64;
        const float* xb = x + ((size_t)b * KDIM + c0) * HW + n0;
        #pragma unroll
        for (int l = 0; l < 16; ++l) {
            int flat = l * 256 + tid;
            int row = flat >> 6, col = flat & 63;
            t[col][row] = f2bf(xb[(size_t)row * HW + col]);
        }
        __syncthreads();
        short* xt = XT + ((size_t)b * HW + n0) * KDIM + c0;
        #pragma unroll
        for (int l = 0; l < 8; ++l) {
            int u = l * 256 + tid;
            int nrow = u >> 5, cp = (u & 31) * 2;
            short2 v = make_short2(t[nrow][cp], t[nrow][cp + 1]);
            *(short2*)(xt + (size_t)nrow * KDIM + cp) = v;
        }
    } else if (bx < 2560) {
        int idx = (bx - 1024) * 256 + tid;     // < 768*512 exactly
        int row = idx >> 9, col = idx & 511;
        int i = col >> 2, s = col & 3;
        float val;
        if (row < 256) {
            int o = row >> 2, r = row & 3;
            val = c1_w[(o * CIN + i) * 4 + ((s - r) & 3)];
        } else {
            int ro = row - 256;
            int o = ro >> 2, r = ro & 3;
            val = v_w[(o * CIN + i) * 4 + ((s - r) & 3)];
        }
        Wb[idx] = f2bf(val);
    } else if (bx < 2672) {
        int idx = (bx - 2560) * 256 + tid;     // < 448*64 exactly
        int o = idx >> 6, k = idx & 63;
        c2wb[idx] = f2bf(o < WMAP_O ? c2_w[o * C2K + k] : 0.f);
        if (idx < WMAP_OP)
            c2bp[idx] = idx < WMAP_O ? c2_b[idx] : 0.f;
    } else {
        *(float4*)(gnstat + tid * 4) = make_float4(0.f, 0.f, 0.f, 0.f);
    }
}

// ---------------------------------------------------------------- MFMA GEMM (2-phase dbuf):
// tvb[b] = bf16( Wb @ X[b] ), + GN partial stats
#define GBM 64
#define GBN 128
#define GBK 64
__global__ __launch_bounds__(256) void gemm_mfma_kernel(
    const short* __restrict__ Wb, const short* __restrict__ XT,
    short* __restrict__ tvb, float* __restrict__ gnstat)
{
    __shared__ short As[2][GBM * GBK];   // 2 x  8 KB
    __shared__ short Bs[2][GBN * GBK];   // 2 x 16 KB
    int b  = blockIdx.z;
    int m0 = blockIdx.y * GBM;
    int n0 = blockIdx.x * GBN;
    int tid = threadIdx.x;
    int lane = tid & 63, wv = tid >> 6;
    int wm = wv & 1, wn = wv >> 1;          // wave tile: 32 rows x 64 cols
    int rl = lane & 15, kg = lane >> 4;
    const short* Ab = Wb + (size_t)m0 * KDIM;
    const short* Bb = XT + ((size_t)b * HW + n0) * KDIM;
    f32x4 acc[2][4] = {};

#define GEMM_STAGE(buf, k0)                                                              \
    do {                                                                                 \
        _Pragma("unroll")                                                                \
        for (int l = 0; l < 2; ++l) {                                                    \
            int c = l * 256 + tid;                                                       \
            int row = c >> 3, kc = c & 7;                                                \
            int kcs = kc ^ (row & 7);                                                    \
            __builtin_amdgcn_global_load_lds(                                            \
                (const AS1 void*)(Ab + (size_t)row * KDIM + (k0) + kcs * 8),             \
                (AS3 void*)(As[buf] + (l * 256 + wv * 64) * 8), 16, 0, 0);               \
        }                                                                                \
        _Pragma("unroll")                                                                \
        for (int l = 0; l < 4; ++l) {                                                    \
            int c = l * 256 + tid;                                                       \
            int row = c >> 3, kc = c & 7;                                                \
            int kcs = kc ^ (row & 7);                                                    \
            __builtin_amdgcn_global_load_lds(                                            \
                (const AS1 void*)(Bb + (size_t)row * KDIM + (k0) + kcs * 8),             \
                (AS3 void*)(Bs[buf] + (l * 256 + wv * 64) * 8), 16, 0, 0);               \
        }                                                                                \
    } while (0)

    GEMM_STAGE(0, 0);
    __syncthreads();
    for (int t = 0; t < KDIM / GBK; ++t) {
        int cur = t & 1;
        if (t < KDIM / GBK - 1) GEMM_STAGE(cur ^ 1, (t + 1) * GBK);
        #pragma unroll
        for (int ks = 0; ks < 2; ++ks) {
            bf16x8 af[2], bfr[4];
            #pragma unroll
            for (int mf = 0; mf < 2; ++mf) {
                int row = wm * 32 + mf * 16 + rl;
                af[mf] = *(const bf16x8*)(As[cur] + row * GBK + ((ks * 4 + kg) ^ (row & 7)) * 8);
            }
            #pragma unroll
            for (int nf = 0; nf < 4; ++nf) {
                int row = wn * 64 + nf * 16 + rl;
                bfr[nf] = *(const bf16x8*)(Bs[cur] + row * GBK + ((ks * 4 + kg) ^ (row & 7)) * 8);
            }
            #pragma unroll
            for (int mf = 0; mf < 2; ++mf)
                #pragma unroll
                for (int nf = 0; nf < 4; ++nf)
                    acc[mf][nf] = __builtin_amdgcn_mfma_f32_16x16x32_bf16(af[mf], bfr[nf], acc[mf][nf], 0, 0, 0);
        }
        __syncthreads();
    }
#undef GEMM_STAGE

    short* Cb = tvb + (size_t)b * MROWS * HW;
    #pragma unroll
    for (int mf = 0; mf < 2; ++mf) {
        int rowb = m0 + wm * 32 + mf * 16 + kg * 4;
        #pragma unroll
        for (int nf = 0; nf < 4; ++nf) {
            int col = n0 + wn * 64 + nf * 16 + rl;
            #pragma unroll
            for (int i = 0; i < 4; ++i)
                Cb[(size_t)(rowb + i) * HW + col] = f2bf(acc[mf][nf][i]);
        }
    }

    // GN partial stats for t rows: each (wave,mf) covers one 4-row group x 64 cols
    if (m0 < TROWS) {
        #pragma unroll
        for (int mf = 0; mf < 2; ++mf) {
            float s = 0.f, sq = 0.f;
            #pragma unroll
            for (int nf = 0; nf < 4; ++nf)
                #pragma unroll
                for (int i = 0; i < 4; ++i) {
                    float v = acc[mf][nf][i];
                    s += v; sq += v * v;
                }
            #pragma unroll
            for (int m = 1; m <= 8; m <<= 1) {
                s  += __shfl_xor(s, m);
                sq += __shfl_xor(sq, m);
            }
            if (rl == 0) {
                int grp = (m0 + wm * 32 + mf * 16 + kg * 4) >> 2;
                atomicAdd(&gnstat[(b * 64 + grp) * 2],     s);
                atomicAdd(&gnstat[(b * 64 + grp) * 2 + 1], sq);
            }
        }
    }
}

// ---------------------------------------------------------------- tkn2: normalize + affine + relu + transpose
__global__ __launch_bounds__(256) void tkn2_kernel(
    const short* __restrict__ tvb, const float* __restrict__ gnstat,
    const float* __restrict__ gn_g, const float* __restrict__ gn_b,
    short* __restrict__ tn)
{
    __shared__ short ts[64][72];
    __shared__ float sc[64], sh[64];
    int b4r = blockIdx.x;
    int b = b4r >> 2, r = b4r & 3;
    int hw0 = blockIdx.y * 64;
    int tid = threadIdx.x;
    if (tid < 64) {
        float s   = gnstat[(b * 64 + tid) * 2];
        float sq  = gnstat[(b * 64 + tid) * 2 + 1];
        float mu  = s * (1.f / 4096.f);
        float var = sq * (1.f / 4096.f) - mu * mu;
        float inv = rsqrtf(var + 1e-5f);
        int ch = tid * 4 + r;
        float g = gn_g[ch], bb = gn_b[ch];
        sc[tid] = inv * g;
        sh[tid] = bb - mu * inv * g;
    }
    #pragma unroll
    for (int l = 0; l < 16; ++l) {
        int flat = l * 256 + tid;
        int c = flat >> 6, hw = flat & 63;
        ts[c][hw] = tvb[((size_t)b * MROWS + c * 4 + r) * HW + hw0 + hw];
    }
    __syncthreads();
    #pragma unroll
    for (int l = 0; l < 2; ++l) {
        int u = l * 256 + tid;
        int hw = u >> 3, c0 = (u & 7) * 8;
        bf16x8 v;
        #pragma unroll
        for (int j = 0; j < 8; ++j) {
            float f = bf2f((unsigned short)ts[c0 + j][hw]);
            f = fmaxf(f * sc[c0 + j] + sh[c0 + j], 0.f);
            v[j] = f2bf(f);
        }
        *(bf16x8*)(tn + ((size_t)b4r * HW + hw0 + hw) * C2K + c0) = v;
    }
}

// ---------------------------------------------------------------- wmap v3b: MFMA GEMM, bf16 out, coalesced epilogue
// wmapB[b4r][o][hw] = bf16( c2bp[o] + sum_c c2wb[o][c] * tn[b4r][hw][c] ), o < 392 only
__global__ __launch_bounds__(256) void wmap3_kernel(
    const short* __restrict__ c2wb, const short* __restrict__ tn,
    const float* __restrict__ c2bp, short* __restrict__ wmapB)
{
    __shared__ short smem[64 * 64 + 128 * 64];   // 24 KB
    short* As = smem;            // [64][64]
    short* Bs = smem + 64 * 64;  // [128][64]
    short* Ps = smem;            // [64][136] = 17 KB, aliases after barrier
    int n0  = blockIdx.x * 128;
    int m0  = blockIdx.y * 64;
    int b4r = blockIdx.z;
    int tid = threadIdx.x;
    int lane = tid & 63, wv = tid >> 6;
    int wm = wv & 1, wn = wv >> 1;
    int rl = lane & 15, kg = lane >> 4;
    const short* Bb = tn + ((size_t)b4r * HW + n0) * C2K;

    #pragma unroll
    for (int l = 0; l < 2; ++l) {
        int c = l * 256 + tid;
        int row = c >> 3, kc = c & 7;
        int kcs = kc ^ (row & 7);
        __builtin_amdgcn_global_load_lds(
            (const AS1 void*)(c2wb + (size_t)(m0 + row) * C2K + kcs * 8),
            (AS3 void*)(As + (l * 256 + wv * 64) * 8), 16, 0, 0);
    }
    #pragma unroll
    for (int l = 0; l < 4; ++l) {
        int c = l * 256 + tid;
        int row = c >> 3, kc = c & 7;
        int kcs = kc ^ (row & 7);
        __builtin_amdgcn_global_load_lds(
            (const AS1 void*)(Bb + (size_t)row * C2K + kcs * 8),
            (AS3 void*)(Bs + (l * 256 + wv * 64) * 8), 16, 0, 0);
    }
    __syncthreads();

    f32x4 acc[2][4] = {};
    #pragma unroll
    for (int ks = 0; ks < 2; ++ks) {
        bf16x8 af[2], bfr[4];
        #pragma unroll
        for (int mf = 0; mf < 2; ++mf) {
            int row = wm * 32 + mf * 16 + rl;
            af[mf] = *(const bf16x8*)(As + row * 64 + ((ks * 4 + kg) ^ (row & 7)) * 8);
        }
        #pragma unroll
        for (int nf = 0; nf < 4; ++nf) {
            int row = wn * 64 + nf * 16 + rl;
            bfr[nf] = *(const bf16x8*)(Bs + row * 64 + ((ks * 4 + kg) ^ (row & 7)) * 8);
        }
        #pragma unroll
        for (int mf = 0; mf < 2; ++mf)
            #pragma unroll
            for (int nf = 0; nf < 4; ++nf)
                acc[mf][nf] = __builtin_amdgcn_mfma_f32_16x16x32_bf16(af[mf], bfr[nf], acc[mf][nf], 0, 0, 0);
    }
    __syncthreads();   // frag reads done -> reuse smem as Ps

    // repack: bias + bf16 into LDS [64][136]
    #pragma unroll
    for (int mf = 0; mf < 2; ++mf) {
        int rowl = wm * 32 + mf * 16 + kg * 4;
        float bi[4];
        #pragma unroll
        for (int i = 0; i < 4; ++i) bi[i] = c2bp[m0 + rowl + i];
        #pragma unroll
        for (int nf = 0; nf < 4; ++nf) {
            int col = wn * 64 + nf * 16 + rl;
            #pragma unroll
            for (int i = 0; i < 4; ++i)
                Ps[(rowl + i) * 136 + col] = f2bf(acc[mf][nf][i] + bi[i]);
        }
    }
    __syncthreads();

    // coalesced store: thread -> (row = tid>>2, 4 x 16B segments), skip pad rows
    int row = tid >> 2, segl = tid & 3;
    if (m0 + row < WMAP_O) {
        short* dst = wmapB + (size_t)b4r * WMAP_OP * HW + (size_t)(m0 + row) * HW + n0;
        #pragma unroll
        for (int s2 = 0; s2 < 4; ++s2) {
            int col = segl * 8 + s2 * 32;
            *(bf16x8*)(dst + col) = *(const bf16x8*)(Ps + row * 136 + col);
        }
    }
}

// ---------------------------------------------------------------- aggregation v6
// grid: (256 bgr, 4 h-strips, 2 c-halves); block: 8 ch x 8 h x 32 w
// lane map keeps agg5's weight sharing: w0q=tid&7, hb=(tid>>3)&1, cc4=(tid>>4)&3, cq=wave
// each lane owns 2 channels (cc4*2+c2); vt 21.1 KB -> ~5 blocks/CU
__global__ __launch_bounds__(256, 5) void agg6_kernel(
    const short* __restrict__ tvb, const short* __restrict__ wmapB,
    float* __restrict__ out)
{
    __shared__ float vt[8][15][44];   // 21.1 KB
    int bx = blockIdx.x;              // b*32 + g*4 + r
    int b = bx >> 5;
    int g = (bx >> 2) & 7;
    int r = bx & 3;
    int h0   = blockIdx.y * 8;
    int half = blockIdx.z;
    int tid  = threadIdx.x;
    int w0q = tid & 7, hb = (tid >> 3) & 1, cc4 = (tid >> 4) & 3, cq = tid >> 6;
    int hl = cq * 2 + hb;             // local h 0..7
    int h = h0 + hl, w0 = w0q * 4;

    int A, Bc, Cc;
    if      (r == 0) { A = 0;  Bc = 7;  Cc = 1;  }
    else if (r == 1) { A = 6;  Bc = -1; Cc = 7;  }
    else if (r == 2) { A = 48; Bc = -7; Cc = -1; }
    else             { A = 42; Bc = 1;  Cc = -7; }

    const short* vpb = tvb + ((size_t)b * MROWS + TROWS) * HW;
    // edge quads (cols 0..3, 36..43) always out of image -> zero
    for (int e = tid; e < 8 * 15 * 3; e += 256) {
        int cc  = e / 45;
        int rem = e - cc * 45;
        int row = rem / 3, q = rem - row * 3;
        int col = (q == 0) ? 0 : (36 + (q - 1) * 4);
        *(float4*)(&vt[cc][row][col]) = make_float4(0.f, 0.f, 0.f, 0.f);
    }
    // interior quads: cols 4..35 <-> gw 0..31 (aligned ushort4)
    for (int f = tid; f < 8 * 15 * 8; f += 256) {
        int cc  = f / 120;
        int rem = f - cc * 120;
        int row = rem >> 3, q = rem & 7;
        int gh = h0 - 3 + row;
        float4 v4 = make_float4(0.f, 0.f, 0.f, 0.f);
        if (gh >= 0 && gh < HH) {
            int ch = (g * GC + half * 8 + cc) * 4 + r;
            ushort4 u = *(const ushort4*)(vpb + (size_t)ch * HW + gh * WWID + q * 4);
            v4 = make_float4(bf2f(u.x), bf2f(u.y), bf2f(u.z), bf2f(u.w));
        }
        *(float4*)(&vt[cc][row][4 + q * 4]) = v4;
    }
    __syncthreads();

    const short* wmb = wmapB + ((size_t)(b * 4 + r) * WMAP_OP + g * 49) * HW + h * WWID + w0;
    float acc[2][4] = {};
    #pragma unroll
    for (int di = 0; di < 7; ++di) {
        float wrf[7][4];
        #pragma unroll
        for (int dj = 0; dj < 7; ++dj) {
            int porig = A + Bc * di + Cc * dj;
            ushort4 wv = *(const ushort4*)(wmb + (size_t)porig * HW);
            wrf[dj][0] = bf2f(wv.x); wrf[dj][1] = bf2f(wv.y);
            wrf[dj][2] = bf2f(wv.z); wrf[dj][3] = bf2f(wv.w);
        }
        #pragma unroll
        for (int c2 = 0; c2 < 2; ++c2) {
            int hc = cc4 * 2 + c2;
            const float* rp = &vt[hc][hl + di][w0];
            float4 q0 = *(const float4*)(rp);
            float4 q1 = *(const float4*)(rp + 4);
            float4 q2 = *(const float4*)(rp + 8);
            float win[12] = {q0.x, q0.y, q0.z, q0.w,
                             q1.x, q1.y, q1.z, q1.w,
                             q2.x, q2.y, q2.z, q2.w};
            #pragma unroll
            for (int dj = 0; dj < 7; ++dj)
                #pragma unroll
                for (int px = 0; px < 4; ++px)
                    acc[c2][px] += wrf[dj][px] * win[px + dj + 1];
        }
    }
    #pragma unroll
    for (int c2 = 0; c2 < 2; ++c2) {
        int ch = (g * GC + half * 8 + cc4 * 2 + c2) * 4 + r;
        float4 o4 = make_float4(acc[c2][0], acc[c2][1], acc[c2][2], acc[c2][3]);
        *(float4*)(out + ((size_t)b * 512 + ch) * HW + h * WWID + w0) = o4;
    }
}

// ---------------------------------------------------------------- launch
extern "C" void kernel_launch(void* const* d_in, const int* in_sizes, int n_in,
                              void* d_out, int out_size, void* d_ws, size_t ws_size,
                              hipStream_t stream)
{
    const float* x    = (const float*)d_in[0];
    const float* v_w  = (const float*)d_in[1];
    const float* c1_w = (const float*)d_in[2];
    const float* gn_g = (const float*)d_in[3];
    const float* gn_b = (const float*)d_in[4];
    const float* c2_w = (const float*)d_in[5];
    const float* c2_b = (const float*)d_in[6];
    float* out = (float*)d_out;

    // workspace layout (XT aliases wmapB; XT dead before wmapB written)
    char* p = (char*)d_ws;
    short* Wb     = (short*)p;           p += (size_t)MROWS * KDIM * 2;        //  0.79 MB
    short* tvb    = (short*)p;           p += (size_t)BB * MROWS * HW * 2;     // 12.6 MB
    short* wmapB  = (short*)p;           p += (size_t)32 * WMAP_OP * HW * 2;   // 29.4 MB
    short* XT     = (short*)wmapB;                                             //  8.4 MB (aliased)
    short* tn     = (short*)p;           p += (size_t)32 * HW * C2K * 2;       //  4.2 MB
    short* c2wb   = (short*)p;           p += (size_t)WMAP_OP * C2K * 2;       // 57 KB
    float* c2bp   = (float*)p;           p += (size_t)WMAP_OP * 4;
    float* gnstat = (float*)p;           p += (size_t)512 * 2 * 4;             //  4 KB

    prep_kernel     <<<2673, 256, 0, stream>>>(x, v_w, c1_w, c2_w, c2_b, XT, Wb, c2wb, c2bp, gnstat);
    gemm_mfma_kernel<<<dim3(HW / GBN, MROWS / GBM, BB), 256, 0, stream>>>(Wb, XT, tvb, gnstat);
    tkn2_kernel     <<<dim3(32, 16), 256, 0, stream>>>(tvb, gnstat, gn_g, gn_b, tn);
    wmap3_kernel    <<<dim3(HW / 128, WMAP_OP / 64, 32), 256, 0, stream>>>(c2wb, tn, c2bp, wmapB);
    agg6_kernel     <<<dim3(BB * NG * 4, 4, 2), 256, 0, stream>>>(tvb, wmapB, out);
}